// Round 6
// baseline (244.476 us; speedup 1.0000x reference)
//
#include <hip/hip_runtime.h>

// ============================================================================
// GPT-2 attention block on gfx950, bf16 MFMA throughout.
//
// R13: attn_fwd QBLK 128 -> 256 (mi 2 -> 4 per wave). R12 arithmetic showed
// attn is DS-read-bound (~16 ds_read_b128 vs 32 MFMA per wave-iter; DS pipe
// per-CU ~3000 cyc vs 620 MFMA cyc per SIMD) with 4x read redundancy across
// waves. Doubling q-rows per wave makes each K/V fragment read feed 4 MFMAs
// (16:64) AND halves the causal tile count (sum 272 -> 144 per bh): LDS
// reads, HBM staging, and barriers all drop ~1.9x; MFMA total unchanged.
// Cost: ~190 VGPR -> launch_bounds(256,2) = 2 blocks/CU (8 waves). Grid 512,
// heavy qtiles (7..4) first, light (0..3) backfill.
// gemm_qkv/prep/gemm_proj frozen at R12 (= R7 structure) for attribution.
// ============================================================================

typedef __bf16 bf16_t;
typedef __bf16 bf16x8 __attribute__((ext_vector_type(8)));
typedef __bf16 bf16x4 __attribute__((ext_vector_type(4)));
typedef float  f32x4  __attribute__((ext_vector_type(4)));
typedef unsigned int u32;
typedef unsigned int u32x4 __attribute__((ext_vector_type(4)));

#define DI __device__ __forceinline__

static constexpr int Bq = 4, Sq = 2048, NXq = 1024, NHq = 16, HDq = 64;

DI void gl2lds16(const void* g, void* l) {
#if defined(__has_builtin)
#if __has_builtin(__builtin_amdgcn_global_load_lds)
  __builtin_amdgcn_global_load_lds(
      (const __attribute__((address_space(1))) void*)g,
      (__attribute__((address_space(3))) void*)l, 16, 0, 0);
  return;
#endif
#endif
  *(bf16x8*)l = *(const bf16x8*)g;
}

DI float fast_exp2(float x) {
#if defined(__has_builtin)
#if __has_builtin(__builtin_amdgcn_exp2f)
  return __builtin_amdgcn_exp2f(x);
#else
  return exp2f(x);
#endif
#else
  return exp2f(x);
#endif
}

DI u32 pk_bf16(float lo, float hi) {
  u32 r;
  asm("v_cvt_pk_bf16_f32 %0, %1, %2" : "=v"(r) : "v"(lo), "v"(hi));
  return r;
}

// ---------------------------------------------------------------------------
// k0: fused prep — X fp32->bf16 (blocks 0..2047), W1 transpose+cvt
// (blocks 2048..5119), W2 transpose+cvt (blocks 5120..6143).
// ---------------------------------------------------------------------------
__global__ __launch_bounds__(256) void prep(
    const float* __restrict__ X, const float* __restrict__ W1,
    const float* __restrict__ W2, bf16_t* __restrict__ Xb,
    bf16_t* __restrict__ Wt1, bf16_t* __restrict__ Wt2) {
  __shared__ float t[32][33];
  const int id = blockIdx.x, tid = threadIdx.x;
  if (id < 2048) {
    const float* src = X + (size_t)id * 4096;
    bf16_t* dst = Xb + (size_t)id * 4096;
#pragma unroll
    for (int i = 0; i < 4; ++i) {
      float4 v = *(const float4*)(src + i * 1024 + tid * 4);
      bf16x4 o;
      o[0] = (bf16_t)v.x; o[1] = (bf16_t)v.y; o[2] = (bf16_t)v.z; o[3] = (bf16_t)v.w;
      *(bf16x4*)(dst + i * 1024 + tid * 4) = o;
    }
    return;
  }
  const float* in; bf16_t* out; int R, C, bx, by;
  if (id < 5120) {  // W1 [1024][3072] -> Wt1 [3072][1024]
    int tI = id - 2048; R = 1024; C = 3072; in = W1; out = Wt1;
    bx = (tI % 96) * 32; by = (tI / 96) * 32;
  } else {          // W2 [1024][1024] -> Wt2 [1024][1024]
    int tI = id - 5120; R = 1024; C = 1024; in = W2; out = Wt2;
    bx = (tI % 32) * 32; by = (tI / 32) * 32;
  }
  int tx = tid & 31, ty = tid >> 5;
#pragma unroll
  for (int i = 0; i < 32; i += 8)
    t[ty + i][tx] = in[(size_t)(by + ty + i) * C + bx + tx];
  __syncthreads();
#pragma unroll
  for (int i = 0; i < 32; i += 8)
    out[(size_t)(bx + ty + i) * R + by + tx] = (bf16_t)t[tx][ty + i];
}

// ---------------------------------------------------------------------------
// GEMM main loop (m97 structure, BK=32) — used by gemm_qkv and gemm_proj.
// ---------------------------------------------------------------------------
DI void gemm_main(const bf16_t* __restrict__ A, const bf16_t* __restrict__ Bt,
                  int K, f32x4 acc[4][4], bf16_t* As, bf16_t* Bs,
                  int lane, int w) {
  const int wy = w >> 1, wx = w & 1;
  const int l15 = lane & 15, quad = lane >> 4;
  for (int kt = 0; kt < K; kt += 32) {
    __syncthreads();
#pragma unroll
    for (int i = 0; i < 2; ++i) {
      int g = w * 2 + i;
      int row = g * 16 + (lane >> 2);
      int ko = kt + (lane & 3) * 8;
      gl2lds16(A + (size_t)row * K + ko, As + g * 512 + lane * 8);
      gl2lds16(Bt + (size_t)row * K + ko, Bs + g * 512 + lane * 8);
    }
    __syncthreads();
    bf16x8 af[4], bfr[4];
#pragma unroll
    for (int mi = 0; mi < 4; ++mi)
      af[mi] = *(const bf16x8*)(As + (wy * 64 + mi * 16 + l15) * 32 + quad * 8);
#pragma unroll
    for (int ni = 0; ni < 4; ++ni)
      bfr[ni] = *(const bf16x8*)(Bs + (wx * 64 + ni * 16 + l15) * 32 + quad * 8);
#pragma unroll
    for (int mi = 0; mi < 4; ++mi)
#pragma unroll
      for (int ni = 0; ni < 4; ++ni)
        acc[mi][ni] = __builtin_amdgcn_mfma_f32_16x16x32_bf16(
            af[mi], bfr[ni], acc[mi][ni], 0, 0, 0);
  }
}

// ---------------------------------------------------------------------------
// k2: QKV GEMM (R7 epilogue/structure). Grid (64,24): x = M-tile (fast).
// ---------------------------------------------------------------------------
__global__ __launch_bounds__(256) void gemm_qkv(
    const bf16_t* __restrict__ X, const bf16_t* __restrict__ Wt,
    const float* __restrict__ bias, bf16_t* __restrict__ qw,
    bf16_t* __restrict__ kw, bf16_t* __restrict__ vtw) {
  __shared__ __align__(16) bf16_t As[128 * 32];
  __shared__ __align__(16) bf16_t Bs[128 * 32];
  const int tid = threadIdx.x, lane = tid & 63, w = tid >> 6;
  const int m0 = blockIdx.x * 128, n0 = blockIdx.y * 128;
  f32x4 acc[4][4];
#pragma unroll
  for (int mi = 0; mi < 4; ++mi)
#pragma unroll
    for (int ni = 0; ni < 4; ++ni) acc[mi][ni] = (f32x4){0.f, 0.f, 0.f, 0.f};
  gemm_main(X + (size_t)m0 * NXq, Wt + (size_t)n0 * NXq, NXq, acc, As, Bs, lane, w);

  const int wy = w >> 1, wx = w & 1, l15 = lane & 15, quad = lane >> 4;
  const float qscale = 0.125f * 1.44269504088896340736f;
#pragma unroll
  for (int mi = 0; mi < 4; ++mi) {
    int rowb = m0 + wy * 64 + mi * 16 + quad * 4;
    int bb = rowb >> 11, sl = rowb & 2047;
#pragma unroll
    for (int ni = 0; ni < 4; ++ni) {
      int col = n0 + wx * 64 + ni * 16 + l15;
      float bv = bias[col];
      f32x4 v = acc[mi][ni];
      int sec = col >> 10;
      int c = col & 1023;
      int h = c >> 6, d = c & 63;
      if (sec == 0) {
#pragma unroll
        for (int r = 0; r < 4; ++r)
          qw[(((size_t)bb * NHq + h) * Sq + sl + r) * HDq + d] =
              (bf16_t)((v[r] + bv) * qscale);
      } else if (sec == 1) {
#pragma unroll
        for (int r = 0; r < 4; ++r)
          kw[(((size_t)bb * NHq + h) * Sq + sl + r) * HDq + d] = (bf16_t)(v[r] + bv);
      } else {
        bf16x4 t;
#pragma unroll
        for (int r = 0; r < 4; ++r) t[r] = (bf16_t)(v[r] + bv);
        *(bf16x4*)(vtw + (((size_t)bb * NHq + h) * HDq + d) * Sq + sl) = t;
      }
    }
  }
}

// ---------------------------------------------------------------------------
// k3: flash attention, causal. R13: 256 q-rows/block (64/wave, mi=4),
// swapped-QK^T in-register softmax (T12), sigma K-row staging,
// double-buffered K/V, 2 blocks/CU.
// ---------------------------------------------------------------------------
__global__ __launch_bounds__(256, 2) void attn_fwd(
    const bf16_t* __restrict__ qw, const bf16_t* __restrict__ kw,
    const bf16_t* __restrict__ vtw, bf16_t* __restrict__ aw) {
  __shared__ __align__(16) bf16_t Ks[2][4096], Vs[2][4096];
  const int tid = threadIdx.x, lane = tid & 63, w = tid >> 6;
  const int l15 = lane & 15, quad = lane >> 4;
  const int q2b = quad >> 1;  // lane bit 5

  const int id = blockIdx.x;
  const int bh = ((id & 7) << 3) | ((id >> 3) & 7);
  const int qsel = id >> 6;                       // [0,8)
  const int qtile = qsel < 4 ? 7 - qsel : qsel - 4;  // heavy first
  const int b = bh >> 4, h = bh & 15;

  const bf16_t* Qg = qw + ((size_t)bh * Sq + qtile * 256) * HDq;
  const bf16_t* Kg = kw + (size_t)bh * Sq * HDq;
  const bf16_t* Vg = vtw + (size_t)bh * HDq * Sq;

  bf16x8 qf[4][2];
#pragma unroll
  for (int mi = 0; mi < 4; ++mi)
#pragma unroll
    for (int ks = 0; ks < 2; ++ks)
      qf[mi][ks] = *(const bf16x8*)(
          Qg + (size_t)((w * 4 + mi) * 16 + l15) * HDq + ks * 32 + quad * 8);

  f32x4 o[4][4];
  float ls[4] = {0.f, 0.f, 0.f, 0.f};
#pragma unroll
  for (int mi = 0; mi < 4; ++mi)
#pragma unroll
    for (int dt = 0; dt < 4; ++dt) o[mi][dt] = (f32x4){0.f, 0.f, 0.f, 0.f};

  // per-wave staging: 2 K-units + 2 V-units.
  // K rows permuted by sigma = swap bits 2<->3 of row-in-16 (global source
  // only; LDS linear) so the PV A-frag is half lane-local.
  const int u0 = w * 2, u1 = w * 2 + 1;
  const int p0 = u0 >> 2, g0 = u0 & 3, p1 = u1 >> 2, g1 = u1 & 3;
  const int rin = lane >> 2;
  const int sig = (rin & 3) | ((rin & 4) << 1) | ((rin & 8) >> 1);
  const size_t kOff0 = (size_t)(g0 * 16 + sig) * HDq + p0 * 32 + (lane & 3) * 8;
  const size_t kOff1 = (size_t)(g1 * 16 + sig) * HDq + p1 * 32 + (lane & 3) * 8;
  const size_t vRow0 = (size_t)(g0 * 16 + rin) * Sq + p0 * 32 + (lane & 3) * 8;
  const size_t vRow1 = (size_t)(g1 * 16 + rin) * Sq + p1 * 32 + (lane & 3) * 8;

  const int jmax = 4 * qtile + 4;

  // prologue: stage tile 0 into buf 0
  gl2lds16(Kg + kOff0,  &Ks[0][u0 * 512 + lane * 8]);
  gl2lds16(Vg + vRow0,  &Vs[0][u0 * 512 + lane * 8]);
  gl2lds16(Kg + kOff1,  &Ks[0][u1 * 512 + lane * 8]);
  gl2lds16(Vg + vRow1,  &Vs[0][u1 * 512 + lane * 8]);

  for (int jt = 0; jt < jmax; ++jt) {
    const int cur = jt & 1;
    // own loads for buf[cur] issued a full iteration ago -> cheap wait
    asm volatile("s_waitcnt vmcnt(0)" ::: "memory");
    __builtin_amdgcn_s_barrier();
    if (jt + 1 < jmax) {
      const int nb = cur ^ 1;
      gl2lds16(Kg + (size_t)(jt + 1) * 64 * HDq + kOff0, &Ks[nb][u0 * 512 + lane * 8]);
      gl2lds16(Vg + vRow0 + (size_t)(jt + 1) * 64,       &Vs[nb][u0 * 512 + lane * 8]);
      gl2lds16(Kg + (size_t)(jt + 1) * 64 * HDq + kOff1, &Ks[nb][u1 * 512 + lane * 8]);
      gl2lds16(Vg + vRow1 + (size_t)(jt + 1) * 64,       &Vs[nb][u1 * 512 + lane * 8]);
    }
    const bf16_t* Kc = &Ks[cur][0];
    const bf16_t* Vc = &Vs[cur][0];

    // ---- QK^T, SWAPPED operands: sc[mi][nt] lane(l15,quad)[r] =
    //      S[q=(w*4+mi)*16+l15][key = jt*64 + nt*16 + sigma(quad*4+r)]
    //      Each kf read feeds 4 MFMAs (mi).
    f32x4 sc[4][4];
#pragma unroll
    for (int mi = 0; mi < 4; ++mi)
#pragma unroll
      for (int nt = 0; nt < 4; ++nt) sc[mi][nt] = (f32x4){0.f, 0.f, 0.f, 0.f};
    __builtin_amdgcn_s_setprio(1);
#pragma unroll
    for (int ks = 0; ks < 2; ++ks)
#pragma unroll
      for (int nt = 0; nt < 4; ++nt) {
        bf16x8 kf = *(const bf16x8*)(Kc + ks * 2048 + nt * 512 + (l15 * 4 + quad) * 8);
#pragma unroll
        for (int mi = 0; mi < 4; ++mi)
          sc[mi][nt] = __builtin_amdgcn_mfma_f32_16x16x32_bf16(kf, qf[mi][ks], sc[mi][nt], 0, 0, 0);
      }
    __builtin_amdgcn_s_setprio(0);

    // causal mask: key = jt*64 + nt*16 + 8*(quad&1) + 4*(quad>>1) + r
    if (jt >= 4 * qtile) {
      const int kb = jt * 64 + ((quad & 1) << 3) + (q2b << 2);
#pragma unroll
      for (int mi = 0; mi < 4; ++mi) {
        int qrow = qtile * 256 + (w * 4 + mi) * 16 + l15;
#pragma unroll
        for (int nt = 0; nt < 4; ++nt)
#pragma unroll
          for (int r = 0; r < 4; ++r)
            if (kb + nt * 16 + r > qrow) sc[mi][nt][r] = -1e30f;
      }
    }

    // ---- in-register P: exp2, pack to bf16, half-local + one xor32 swap.
    bf16x8 pa[4][2];
#pragma unroll
    for (int mi = 0; mi < 4; ++mi) {
      float pv[4][4];
#pragma unroll
      for (int nt = 0; nt < 4; ++nt)
#pragma unroll
        for (int r = 0; r < 4; ++r) {
          float p = fast_exp2(sc[mi][nt][r]);
          pv[nt][r] = p;
          ls[mi] += p;
        }
      u32 c0[4], c1[4];
#pragma unroll
      for (int nt = 0; nt < 4; ++nt) {
        c0[nt] = pk_bf16(pv[nt][0], pv[nt][1]);
        c1[nt] = pk_bf16(pv[nt][2], pv[nt][3]);
      }
#pragma unroll
      for (int kk = 0; kk < 2; ++kk) {
        // own: register nt = 2kk+q2, covers j in [4*q2, 4*q2+4)
        u32 oc0 = q2b ? c0[2 * kk + 1] : c0[2 * kk];
        u32 oc1 = q2b ? c1[2 * kk + 1] : c1[2 * kk];
        // send the register the xor32 partner needs (its nt = 2kk + own q2)
        u32 sd0 = q2b ? c0[2 * kk] : c0[2 * kk + 1];
        u32 sd1 = q2b ? c1[2 * kk] : c1[2 * kk + 1];
        u32 rc0 = (u32)__shfl_xor((int)sd0, 32);
        u32 rc1 = (u32)__shfl_xor((int)sd1, 32);
        u32x4 wv;
        wv[0] = q2b ? rc0 : oc0;
        wv[1] = q2b ? rc1 : oc1;
        wv[2] = q2b ? oc0 : rc0;
        wv[3] = q2b ? oc1 : rc1;
        pa[mi][kk] = __builtin_bit_cast(bf16x8, wv);
      }
    }

    // ---- PV: each bv read feeds 4 MFMAs (mi).
    __builtin_amdgcn_s_setprio(1);
#pragma unroll
    for (int kk = 0; kk < 2; ++kk) {
#pragma unroll
      for (int dt = 0; dt < 4; ++dt) {
        bf16x8 bv = *(const bf16x8*)(Vc + kk * 2048 + dt * 512 + (l15 * 4 + quad) * 8);
#pragma unroll
        for (int mi = 0; mi < 4; ++mi)
          o[mi][dt] = __builtin_amdgcn_mfma_f32_16x16x32_bf16(pa[mi][kk], bv, o[mi][dt], 0, 0, 0);
      }
    }
    __builtin_amdgcn_s_setprio(0);
  }

  // row sums: cross-quad reduce, then redistribute per output row.
  float linv[4][4];
#pragma unroll
  for (int mi = 0; mi < 4; ++mi) {
    float s = ls[mi];
    s += __shfl_xor(s, 16);
    s += __shfl_xor(s, 32);
#pragma unroll
    for (int r = 0; r < 4; ++r)
      linv[mi][r] = 1.f / __shfl(s, quad * 4 + r);
  }

#pragma unroll
  for (int mi = 0; mi < 4; ++mi) {
    int s0 = qtile * 256 + (w * 4 + mi) * 16 + quad * 4;
#pragma unroll
    for (int dt = 0; dt < 4; ++dt) {
      int col = h * 64 + dt * 16 + l15;
#pragma unroll
      for (int r = 0; r < 4; ++r)
        aw[((size_t)b * Sq + s0 + r) * NXq + col] = (bf16_t)(o[mi][dt][r] * linv[mi][r]);
    }
  }
}

// ---------------------------------------------------------------------------
// k4: output projection GEMM -> fp32 out + bias (unchanged).
// ---------------------------------------------------------------------------
__global__ __launch_bounds__(256) void gemm_proj(
    const bf16_t* __restrict__ Aa, const bf16_t* __restrict__ Wt,
    const float* __restrict__ bias, float* __restrict__ out) {
  __shared__ __align__(16) bf16_t As[128 * 32];
  __shared__ __align__(16) bf16_t Bs[128 * 32];
  const int tid = threadIdx.x, lane = tid & 63, w = tid >> 6;
  const int m0 = blockIdx.x * 128, n0 = blockIdx.y * 128;
  f32x4 acc[4][4];
#pragma unroll
  for (int mi = 0; mi < 4; ++mi)
#pragma unroll
    for (int ni = 0; ni < 4; ++ni) acc[mi][ni] = (f32x4){0.f, 0.f, 0.f, 0.f};
  gemm_main(Aa + (size_t)m0 * NXq, Wt + (size_t)n0 * NXq, NXq, acc, As, Bs, lane, w);

  const int wy = w >> 1, wx = w & 1, l15 = lane & 15, quad = lane >> 4;
#pragma unroll
  for (int mi = 0; mi < 4; ++mi) {
    int rowb = m0 + wy * 64 + mi * 16 + quad * 4;
#pragma unroll
    for (int ni = 0; ni < 4; ++ni) {
      int col = n0 + wx * 64 + ni * 16 + l15;
      float bv = bias[col];
#pragma unroll
      for (int r = 0; r < 4; ++r)
        out[(size_t)(rowb + r) * NXq + col] = acc[mi][ni][r] + bv;
    }
  }
}

// ---------------------------------------------------------------------------
// launch
// ---------------------------------------------------------------------------
extern "C" void kernel_launch(void* const* d_in, const int* in_sizes, int n_in,
                              void* d_out, int out_size, void* d_ws, size_t ws_size,
                              hipStream_t stream) {
  const float* hidden   = (const float*)d_in[0];
  const float* c_attn_w = (const float*)d_in[1];
  const float* c_attn_b = (const float*)d_in[2];
  const float* c_proj_w = (const float*)d_in[3];
  const float* c_proj_b = (const float*)d_in[4];
  float* out = (float*)d_out;

  char* ws = (char*)d_ws;
  const size_t szX   = (size_t)8192 * 1024 * 2;
  const size_t szW1  = (size_t)3072 * 1024 * 2;
  const size_t szW2  = (size_t)1024 * 1024 * 2;
  const size_t szQKV = (size_t)Bq * NHq * Sq * HDq * 2;
  bf16_t* Xb  = (bf16_t*)(ws);
  bf16_t* Wt1 = (bf16_t*)(ws + szX);
  bf16_t* Wt2 = (bf16_t*)(ws + szX + szW1);
  bf16_t* qwp = (bf16_t*)(ws + szX + szW1 + szW2);
  bf16_t* kwp = (bf16_t*)(ws + szX + szW1 + szW2 + szQKV);
  bf16_t* vtp = (bf16_t*)(ws + szX + szW1 + szW2 + 2 * szQKV);
  bf16_t* awp = (bf16_t*)(ws + szX + szW1 + szW2 + 3 * szQKV);
  if (ws_size < szX + szW1 + szW2 + 4 * szQKV) return;

  prep<<<dim3(6144), dim3(256), 0, stream>>>(hidden, c_attn_w, c_proj_w,
                                             Xb, Wt1, Wt2);
  gemm_qkv<<<dim3(64, 24), dim3(256), 0, stream>>>(
      Xb, Wt1, c_attn_b, qwp, kwp, vtp);
  attn_fwd<<<dim3(512), dim3(256), 0, stream>>>(qwp, kwp, vtp, awp);
  gemm_proj<<<dim3(64, 8), dim3(256), 0, stream>>>(
      awp, Wt2, c_proj_b, out);
}

// Round 7
// 232.562 us; speedup vs baseline: 1.0512x; 1.0512x over previous
//
#include <hip/hip_runtime.h>

// ============================================================================
// GPT-2 attention block on gfx950, bf16 MFMA throughout.
//
// R14 = R12 restored (best measured: 232.9 us). R13's mi=4 attn regressed
// +11.6 us: ~230 VGPR -> 2 blocks/CU (2 waves/SIMD) could not hide the
// per-iter serial chain (load-wait -> QK^T -> exp/pack VALU -> PV); attn is
// latency-bound below ~16 waves/CU, occupancy > DS savings. R12's attn
// (mi=2, 4 blocks/CU, in-register softmax) is the local optimum under the
// 128-VGPR/4-wave budget.
//  - gemm_qkv: R7 128x128 m97 structure, grid (64,24) m-fast. 4 structural
//    rewrites (R8/R9/R11) all 70-80 us -> parked at ~72 us (K=1024 regime).
//  - attn_fwd: swapped-QK^T (mfma(kf,qf)) in-register softmax; sigma K-row
//    staging (swap bits 2<->3) makes PV A-frag half lane-local, other half
//    one shfl_xor(32); v_cvt_pk_bf16_f32 packs; no P LDS; dbuf K/V;
//    bh mapping confines each head's 16 q-blocks to one XCD (4MB = L2).
//  - prep: fused cvt + both W transposes; proj: m97 structure.
// ============================================================================

typedef __bf16 bf16_t;
typedef __bf16 bf16x8 __attribute__((ext_vector_type(8)));
typedef __bf16 bf16x4 __attribute__((ext_vector_type(4)));
typedef float  f32x4  __attribute__((ext_vector_type(4)));
typedef unsigned int u32;
typedef unsigned int u32x4 __attribute__((ext_vector_type(4)));

#define DI __device__ __forceinline__

static constexpr int Bq = 4, Sq = 2048, NXq = 1024, NHq = 16, HDq = 64;

DI void gl2lds16(const void* g, void* l) {
#if defined(__has_builtin)
#if __has_builtin(__builtin_amdgcn_global_load_lds)
  __builtin_amdgcn_global_load_lds(
      (const __attribute__((address_space(1))) void*)g,
      (__attribute__((address_space(3))) void*)l, 16, 0, 0);
  return;
#endif
#endif
  *(bf16x8*)l = *(const bf16x8*)g;
}

DI float fast_exp2(float x) {
#if defined(__has_builtin)
#if __has_builtin(__builtin_amdgcn_exp2f)
  return __builtin_amdgcn_exp2f(x);
#else
  return exp2f(x);
#endif
#else
  return exp2f(x);
#endif
}

DI u32 pk_bf16(float lo, float hi) {
  u32 r;
  asm("v_cvt_pk_bf16_f32 %0, %1, %2" : "=v"(r) : "v"(lo), "v"(hi));
  return r;
}

// ---------------------------------------------------------------------------
// k0: fused prep — X fp32->bf16 (blocks 0..2047), W1 transpose+cvt
// (blocks 2048..5119), W2 transpose+cvt (blocks 5120..6143).
// ---------------------------------------------------------------------------
__global__ __launch_bounds__(256) void prep(
    const float* __restrict__ X, const float* __restrict__ W1,
    const float* __restrict__ W2, bf16_t* __restrict__ Xb,
    bf16_t* __restrict__ Wt1, bf16_t* __restrict__ Wt2) {
  __shared__ float t[32][33];
  const int id = blockIdx.x, tid = threadIdx.x;
  if (id < 2048) {
    const float* src = X + (size_t)id * 4096;
    bf16_t* dst = Xb + (size_t)id * 4096;
#pragma unroll
    for (int i = 0; i < 4; ++i) {
      float4 v = *(const float4*)(src + i * 1024 + tid * 4);
      bf16x4 o;
      o[0] = (bf16_t)v.x; o[1] = (bf16_t)v.y; o[2] = (bf16_t)v.z; o[3] = (bf16_t)v.w;
      *(bf16x4*)(dst + i * 1024 + tid * 4) = o;
    }
    return;
  }
  const float* in; bf16_t* out; int R, C, bx, by;
  if (id < 5120) {  // W1 [1024][3072] -> Wt1 [3072][1024]
    int tI = id - 2048; R = 1024; C = 3072; in = W1; out = Wt1;
    bx = (tI % 96) * 32; by = (tI / 96) * 32;
  } else {          // W2 [1024][1024] -> Wt2 [1024][1024]
    int tI = id - 5120; R = 1024; C = 1024; in = W2; out = Wt2;
    bx = (tI % 32) * 32; by = (tI / 32) * 32;
  }
  int tx = tid & 31, ty = tid >> 5;
#pragma unroll
  for (int i = 0; i < 32; i += 8)
    t[ty + i][tx] = in[(size_t)(by + ty + i) * C + bx + tx];
  __syncthreads();
#pragma unroll
  for (int i = 0; i < 32; i += 8)
    out[(size_t)(bx + ty + i) * R + by + tx] = (bf16_t)t[tx][ty + i];
}

// ---------------------------------------------------------------------------
// GEMM main loop (m97 structure, BK=32) — used by gemm_qkv and gemm_proj.
// ---------------------------------------------------------------------------
DI void gemm_main(const bf16_t* __restrict__ A, const bf16_t* __restrict__ Bt,
                  int K, f32x4 acc[4][4], bf16_t* As, bf16_t* Bs,
                  int lane, int w) {
  const int wy = w >> 1, wx = w & 1;
  const int l15 = lane & 15, quad = lane >> 4;
  for (int kt = 0; kt < K; kt += 32) {
    __syncthreads();
#pragma unroll
    for (int i = 0; i < 2; ++i) {
      int g = w * 2 + i;
      int row = g * 16 + (lane >> 2);
      int ko = kt + (lane & 3) * 8;
      gl2lds16(A + (size_t)row * K + ko, As + g * 512 + lane * 8);
      gl2lds16(Bt + (size_t)row * K + ko, Bs + g * 512 + lane * 8);
    }
    __syncthreads();
    bf16x8 af[4], bfr[4];
#pragma unroll
    for (int mi = 0; mi < 4; ++mi)
      af[mi] = *(const bf16x8*)(As + (wy * 64 + mi * 16 + l15) * 32 + quad * 8);
#pragma unroll
    for (int ni = 0; ni < 4; ++ni)
      bfr[ni] = *(const bf16x8*)(Bs + (wx * 64 + ni * 16 + l15) * 32 + quad * 8);
#pragma unroll
    for (int mi = 0; mi < 4; ++mi)
#pragma unroll
      for (int ni = 0; ni < 4; ++ni)
        acc[mi][ni] = __builtin_amdgcn_mfma_f32_16x16x32_bf16(
            af[mi], bfr[ni], acc[mi][ni], 0, 0, 0);
  }
}

// ---------------------------------------------------------------------------
// k2: QKV GEMM (R7 epilogue/structure). Grid (64,24): x = M-tile (fast).
// ---------------------------------------------------------------------------
__global__ __launch_bounds__(256) void gemm_qkv(
    const bf16_t* __restrict__ X, const bf16_t* __restrict__ Wt,
    const float* __restrict__ bias, bf16_t* __restrict__ qw,
    bf16_t* __restrict__ kw, bf16_t* __restrict__ vtw) {
  __shared__ __align__(16) bf16_t As[128 * 32];
  __shared__ __align__(16) bf16_t Bs[128 * 32];
  const int tid = threadIdx.x, lane = tid & 63, w = tid >> 6;
  const int m0 = blockIdx.x * 128, n0 = blockIdx.y * 128;
  f32x4 acc[4][4];
#pragma unroll
  for (int mi = 0; mi < 4; ++mi)
#pragma unroll
    for (int ni = 0; ni < 4; ++ni) acc[mi][ni] = (f32x4){0.f, 0.f, 0.f, 0.f};
  gemm_main(X + (size_t)m0 * NXq, Wt + (size_t)n0 * NXq, NXq, acc, As, Bs, lane, w);

  const int wy = w >> 1, wx = w & 1, l15 = lane & 15, quad = lane >> 4;
  const float qscale = 0.125f * 1.44269504088896340736f;
#pragma unroll
  for (int mi = 0; mi < 4; ++mi) {
    int rowb = m0 + wy * 64 + mi * 16 + quad * 4;
    int bb = rowb >> 11, sl = rowb & 2047;
#pragma unroll
    for (int ni = 0; ni < 4; ++ni) {
      int col = n0 + wx * 64 + ni * 16 + l15;
      float bv = bias[col];
      f32x4 v = acc[mi][ni];
      int sec = col >> 10;
      int c = col & 1023;
      int h = c >> 6, d = c & 63;
      if (sec == 0) {
#pragma unroll
        for (int r = 0; r < 4; ++r)
          qw[(((size_t)bb * NHq + h) * Sq + sl + r) * HDq + d] =
              (bf16_t)((v[r] + bv) * qscale);
      } else if (sec == 1) {
#pragma unroll
        for (int r = 0; r < 4; ++r)
          kw[(((size_t)bb * NHq + h) * Sq + sl + r) * HDq + d] = (bf16_t)(v[r] + bv);
      } else {
        bf16x4 t;
#pragma unroll
        for (int r = 0; r < 4; ++r) t[r] = (bf16_t)(v[r] + bv);
        *(bf16x4*)(vtw + (((size_t)bb * NHq + h) * HDq + d) * Sq + sl) = t;
      }
    }
  }
}

// ---------------------------------------------------------------------------
// k3: flash attention, causal. R12 version: swapped-QK^T in-register softmax
// (T12), sigma K-row staging, double-buffered K/V, 4 blocks/CU.
// ---------------------------------------------------------------------------
__global__ __launch_bounds__(256, 4) void attn_fwd(
    const bf16_t* __restrict__ qw, const bf16_t* __restrict__ kw,
    const bf16_t* __restrict__ vtw, bf16_t* __restrict__ aw) {
  __shared__ __align__(16) bf16_t Ks[2][4096], Vs[2][4096];
  const int tid = threadIdx.x, lane = tid & 63, w = tid >> 6;
  const int l15 = lane & 15, quad = lane >> 4;
  const int q2b = quad >> 1;  // lane bit 5

  const int id = blockIdx.x;
  const int bh = ((id & 7) << 3) | ((id >> 3) & 7);
  const int k4 = (id >> 6) & 3, quarter = id >> 8;
  int qtile;
  if (quarter == 0)      qtile = 15 - k4;
  else if (quarter == 1) qtile = 8 + k4;
  else if (quarter == 2) qtile = 7 - k4;
  else                   qtile = k4;
  const int b = bh >> 4, h = bh & 15;

  const bf16_t* Qg = qw + ((size_t)bh * Sq + qtile * 128) * HDq;
  const bf16_t* Kg = kw + (size_t)bh * Sq * HDq;
  const bf16_t* Vg = vtw + (size_t)bh * HDq * Sq;

  bf16x8 qf[2][2];
#pragma unroll
  for (int mi = 0; mi < 2; ++mi)
#pragma unroll
    for (int ks = 0; ks < 2; ++ks)
      qf[mi][ks] = *(const bf16x8*)(
          Qg + (size_t)((w * 2 + mi) * 16 + l15) * HDq + ks * 32 + quad * 8);

  f32x4 o[2][4];
  float ls[2] = {0.f, 0.f};
#pragma unroll
  for (int mi = 0; mi < 2; ++mi)
#pragma unroll
    for (int dt = 0; dt < 4; ++dt) o[mi][dt] = (f32x4){0.f, 0.f, 0.f, 0.f};

  // per-wave staging: 2 K-units + 2 V-units.
  // K rows permuted by sigma = swap bits 2<->3 of row-in-16 (global source
  // only; LDS linear) so the PV A-frag is half lane-local.
  const int u0 = w * 2, u1 = w * 2 + 1;
  const int p0 = u0 >> 2, g0 = u0 & 3, p1 = u1 >> 2, g1 = u1 & 3;
  const int rin = lane >> 2;
  const int sig = (rin & 3) | ((rin & 4) << 1) | ((rin & 8) >> 1);
  const size_t kOff0 = (size_t)(g0 * 16 + sig) * HDq + p0 * 32 + (lane & 3) * 8;
  const size_t kOff1 = (size_t)(g1 * 16 + sig) * HDq + p1 * 32 + (lane & 3) * 8;
  const size_t vRow0 = (size_t)(g0 * 16 + rin) * Sq + p0 * 32 + (lane & 3) * 8;
  const size_t vRow1 = (size_t)(g1 * 16 + rin) * Sq + p1 * 32 + (lane & 3) * 8;

  const int jmax = 2 * qtile + 2;

  // prologue: stage tile 0 into buf 0
  gl2lds16(Kg + kOff0,  &Ks[0][u0 * 512 + lane * 8]);
  gl2lds16(Vg + vRow0,  &Vs[0][u0 * 512 + lane * 8]);
  gl2lds16(Kg + kOff1,  &Ks[0][u1 * 512 + lane * 8]);
  gl2lds16(Vg + vRow1,  &Vs[0][u1 * 512 + lane * 8]);

  for (int jt = 0; jt < jmax; ++jt) {
    const int cur = jt & 1;
    // own loads for buf[cur] issued a full iteration ago -> cheap wait
    asm volatile("s_waitcnt vmcnt(0)" ::: "memory");
    __builtin_amdgcn_s_barrier();
    if (jt + 1 < jmax) {
      const int nb = cur ^ 1;
      gl2lds16(Kg + (size_t)(jt + 1) * 64 * HDq + kOff0, &Ks[nb][u0 * 512 + lane * 8]);
      gl2lds16(Vg + vRow0 + (size_t)(jt + 1) * 64,       &Vs[nb][u0 * 512 + lane * 8]);
      gl2lds16(Kg + (size_t)(jt + 1) * 64 * HDq + kOff1, &Ks[nb][u1 * 512 + lane * 8]);
      gl2lds16(Vg + vRow1 + (size_t)(jt + 1) * 64,       &Vs[nb][u1 * 512 + lane * 8]);
    }
    const bf16_t* Kc = &Ks[cur][0];
    const bf16_t* Vc = &Vs[cur][0];

    // ---- QK^T, SWAPPED operands: sc[mi][nt] lane(l15,quad)[r] =
    //      S[q=(w*2+mi)*16+l15][key = jt*64 + nt*16 + sigma(quad*4+r)]
    f32x4 sc[2][4];
#pragma unroll
    for (int mi = 0; mi < 2; ++mi)
#pragma unroll
      for (int nt = 0; nt < 4; ++nt) sc[mi][nt] = (f32x4){0.f, 0.f, 0.f, 0.f};
    __builtin_amdgcn_s_setprio(1);
#pragma unroll
    for (int ks = 0; ks < 2; ++ks)
#pragma unroll
      for (int nt = 0; nt < 4; ++nt) {
        bf16x8 kf = *(const bf16x8*)(Kc + ks * 2048 + nt * 512 + (l15 * 4 + quad) * 8);
        sc[0][nt] = __builtin_amdgcn_mfma_f32_16x16x32_bf16(kf, qf[0][ks], sc[0][nt], 0, 0, 0);
        sc[1][nt] = __builtin_amdgcn_mfma_f32_16x16x32_bf16(kf, qf[1][ks], sc[1][nt], 0, 0, 0);
      }
    __builtin_amdgcn_s_setprio(0);

    // causal mask: key = jt*64 + nt*16 + 8*(quad&1) + 4*(quad>>1) + r
    if (jt >= 2 * qtile) {
      const int kb = jt * 64 + ((quad & 1) << 3) + (q2b << 2);
#pragma unroll
      for (int mi = 0; mi < 2; ++mi) {
        int qrow = qtile * 128 + (w * 2 + mi) * 16 + l15;
#pragma unroll
        for (int nt = 0; nt < 4; ++nt)
#pragma unroll
          for (int r = 0; r < 4; ++r)
            if (kb + nt * 16 + r > qrow) sc[mi][nt][r] = -1e30f;
      }
    }

    // ---- in-register P: exp2, pack to bf16, half-local + one xor32 swap.
    bf16x8 pa[2][2];
#pragma unroll
    for (int mi = 0; mi < 2; ++mi) {
      float pv[4][4];
#pragma unroll
      for (int nt = 0; nt < 4; ++nt)
#pragma unroll
        for (int r = 0; r < 4; ++r) {
          float p = fast_exp2(sc[mi][nt][r]);
          pv[nt][r] = p;
          ls[mi] += p;
        }
      u32 c0[4], c1[4];
#pragma unroll
      for (int nt = 0; nt < 4; ++nt) {
        c0[nt] = pk_bf16(pv[nt][0], pv[nt][1]);
        c1[nt] = pk_bf16(pv[nt][2], pv[nt][3]);
      }
#pragma unroll
      for (int kk = 0; kk < 2; ++kk) {
        // own: register nt = 2kk+q2, covers j in [4*q2, 4*q2+4)
        u32 oc0 = q2b ? c0[2 * kk + 1] : c0[2 * kk];
        u32 oc1 = q2b ? c1[2 * kk + 1] : c1[2 * kk];
        // send the register the xor32 partner needs (its nt = 2kk + own q2)
        u32 sd0 = q2b ? c0[2 * kk] : c0[2 * kk + 1];
        u32 sd1 = q2b ? c1[2 * kk] : c1[2 * kk + 1];
        u32 rc0 = (u32)__shfl_xor((int)sd0, 32);
        u32 rc1 = (u32)__shfl_xor((int)sd1, 32);
        u32x4 wv;
        wv[0] = q2b ? rc0 : oc0;
        wv[1] = q2b ? rc1 : oc1;
        wv[2] = q2b ? oc0 : rc0;
        wv[3] = q2b ? oc1 : rc1;
        pa[mi][kk] = __builtin_bit_cast(bf16x8, wv);
      }
    }

    // ---- PV
    __builtin_amdgcn_s_setprio(1);
#pragma unroll
    for (int kk = 0; kk < 2; ++kk) {
#pragma unroll
      for (int dt = 0; dt < 4; ++dt) {
        bf16x8 bv = *(const bf16x8*)(Vc + kk * 2048 + dt * 512 + (l15 * 4 + quad) * 8);
        o[0][dt] = __builtin_amdgcn_mfma_f32_16x16x32_bf16(pa[0][kk], bv, o[0][dt], 0, 0, 0);
        o[1][dt] = __builtin_amdgcn_mfma_f32_16x16x32_bf16(pa[1][kk], bv, o[1][dt], 0, 0, 0);
      }
    }
    __builtin_amdgcn_s_setprio(0);
  }

  // row sums: cross-quad reduce, then redistribute per output row.
  float linv[2][4];
#pragma unroll
  for (int mi = 0; mi < 2; ++mi) {
    float s = ls[mi];
    s += __shfl_xor(s, 16);
    s += __shfl_xor(s, 32);
#pragma unroll
    for (int r = 0; r < 4; ++r)
      linv[mi][r] = 1.f / __shfl(s, quad * 4 + r);
  }

#pragma unroll
  for (int mi = 0; mi < 2; ++mi) {
    int s0 = qtile * 128 + (w * 2 + mi) * 16 + quad * 4;
#pragma unroll
    for (int dt = 0; dt < 4; ++dt) {
      int col = h * 64 + dt * 16 + l15;
#pragma unroll
      for (int r = 0; r < 4; ++r)
        aw[((size_t)b * Sq + s0 + r) * NXq + col] = (bf16_t)(o[mi][dt][r] * linv[mi][r]);
    }
  }
}

// ---------------------------------------------------------------------------
// k4: output projection GEMM -> fp32 out + bias (unchanged).
// ---------------------------------------------------------------------------
__global__ __launch_bounds__(256) void gemm_proj(
    const bf16_t* __restrict__ Aa, const bf16_t* __restrict__ Wt,
    const float* __restrict__ bias, float* __restrict__ out) {
  __shared__ __align__(16) bf16_t As[128 * 32];
  __shared__ __align__(16) bf16_t Bs[128 * 32];
  const int tid = threadIdx.x, lane = tid & 63, w = tid >> 6;
  const int m0 = blockIdx.x * 128, n0 = blockIdx.y * 128;
  f32x4 acc[4][4];
#pragma unroll
  for (int mi = 0; mi < 4; ++mi)
#pragma unroll
    for (int ni = 0; ni < 4; ++ni) acc[mi][ni] = (f32x4){0.f, 0.f, 0.f, 0.f};
  gemm_main(Aa + (size_t)m0 * NXq, Wt + (size_t)n0 * NXq, NXq, acc, As, Bs, lane, w);

  const int wy = w >> 1, wx = w & 1, l15 = lane & 15, quad = lane >> 4;
#pragma unroll
  for (int mi = 0; mi < 4; ++mi) {
    int rowb = m0 + wy * 64 + mi * 16 + quad * 4;
#pragma unroll
    for (int ni = 0; ni < 4; ++ni) {
      int col = n0 + wx * 64 + ni * 16 + l15;
      float bv = bias[col];
#pragma unroll
      for (int r = 0; r < 4; ++r)
        out[(size_t)(rowb + r) * NXq + col] = acc[mi][ni][r] + bv;
    }
  }
}

// ---------------------------------------------------------------------------
// launch
// ---------------------------------------------------------------------------
extern "C" void kernel_launch(void* const* d_in, const int* in_sizes, int n_in,
                              void* d_out, int out_size, void* d_ws, size_t ws_size,
                              hipStream_t stream) {
  const float* hidden   = (const float*)d_in[0];
  const float* c_attn_w = (const float*)d_in[1];
  const float* c_attn_b = (const float*)d_in[2];
  const float* c_proj_w = (const float*)d_in[3];
  const float* c_proj_b = (const float*)d_in[4];
  float* out = (float*)d_out;

  char* ws = (char*)d_ws;
  const size_t szX   = (size_t)8192 * 1024 * 2;
  const size_t szW1  = (size_t)3072 * 1024 * 2;
  const size_t szW2  = (size_t)1024 * 1024 * 2;
  const size_t szQKV = (size_t)Bq * NHq * Sq * HDq * 2;
  bf16_t* Xb  = (bf16_t*)(ws);
  bf16_t* Wt1 = (bf16_t*)(ws + szX);
  bf16_t* Wt2 = (bf16_t*)(ws + szX + szW1);
  bf16_t* qwp = (bf16_t*)(ws + szX + szW1 + szW2);
  bf16_t* kwp = (bf16_t*)(ws + szX + szW1 + szW2 + szQKV);
  bf16_t* vtp = (bf16_t*)(ws + szX + szW1 + szW2 + 2 * szQKV);
  bf16_t* awp = (bf16_t*)(ws + szX + szW1 + szW2 + 3 * szQKV);
  if (ws_size < szX + szW1 + szW2 + 4 * szQKV) return;

  prep<<<dim3(6144), dim3(256), 0, stream>>>(hidden, c_attn_w, c_proj_w,
                                             Xb, Wt1, Wt2);
  gemm_qkv<<<dim3(64, 24), dim3(256), 0, stream>>>(
      Xb, Wt1, c_attn_b, qwp, kwp, vtp);
  attn_fwd<<<dim3(1024), dim3(256), 0, stream>>>(qwp, kwp, vtp, awp);
  gemm_proj<<<dim3(64, 8), dim3(256), 0, stream>>>(
      awp, Wt2, c_proj_b, out);
}

// Round 9
// 231.657 us; speedup vs baseline: 1.0553x; 1.0039x over previous
//
#include <hip/hip_runtime.h>

// ============================================================================
// GPT-2 attention block on gfx950, bf16 MFMA throughout.
//
// R16 = R14 restored verbatim (twice-verified best: 232.9 / 232.6 us).
// R15's V-fragment hoist FAILED correctness (absmax 6.5e-2 > 3.06e-2):
// detaching the V ds_reads from their consuming MFMAs removed the implicit
// lgkm-wait anchor; raw s_barrier is not a compiler memory fence, and under
// unroll-x2 (cur = jt&1) the free-floating addrspace(3) loads can migrate
// across the vmcnt/barrier pair into the staging window (rule-#18 class).
// Reverted — the ~3-6 us upside doesn't justify a silent-corruption mode.
//
// Ledger:
//  - gemm_qkv: R7 128x128 m97 structure, grid (64,24) m-fast, ~72 us.
//    Parked: R8/R9/R11 structural rewrites all 70-80 us; K=1024 8-phase
//    regime <=848 TF (m248) and 384-block packing -> no headroom.
//  - attn_fwd: R12 local optimum. Swapped-QK^T (mfma(kf,qf)) in-register
//    softmax (T12); sigma K-row staging (swap bits 2<->3) -> PV A-frag half
//    lane-local + one shfl_xor(32); v_cvt_pk_bf16_f32 packs; no P LDS;
//    dbuf K/V; 4 blocks/CU; bh->XCD L2 confinement. mi=4 variant regressed
//    (occupancy cliff); V-hoist variant corrupts (above).
//  - prep: fused cvt + W transposes (memory-bound ~72 MB).
//  - gemm_proj: m97 structure.
// ============================================================================

typedef __bf16 bf16_t;
typedef __bf16 bf16x8 __attribute__((ext_vector_type(8)));
typedef __bf16 bf16x4 __attribute__((ext_vector_type(4)));
typedef float  f32x4  __attribute__((ext_vector_type(4)));
typedef unsigned int u32;
typedef unsigned int u32x4 __attribute__((ext_vector_type(4)));

#define DI __device__ __forceinline__

static constexpr int Bq = 4, Sq = 2048, NXq = 1024, NHq = 16, HDq = 64;

DI void gl2lds16(const void* g, void* l) {
#if defined(__has_builtin)
#if __has_builtin(__builtin_amdgcn_global_load_lds)
  __builtin_amdgcn_global_load_lds(
      (const __attribute__((address_space(1))) void*)g,
      (__attribute__((address_space(3))) void*)l, 16, 0, 0);
  return;
#endif
#endif
  *(bf16x8*)l = *(const bf16x8*)g;
}

DI float fast_exp2(float x) {
#if defined(__has_builtin)
#if __has_builtin(__builtin_amdgcn_exp2f)
  return __builtin_amdgcn_exp2f(x);
#else
  return exp2f(x);
#endif
#else
  return exp2f(x);
#endif
}

DI u32 pk_bf16(float lo, float hi) {
  u32 r;
  asm("v_cvt_pk_bf16_f32 %0, %1, %2" : "=v"(r) : "v"(lo), "v"(hi));
  return r;
}

// ---------------------------------------------------------------------------
// k0: fused prep — X fp32->bf16 (blocks 0..2047), W1 transpose+cvt
// (blocks 2048..5119), W2 transpose+cvt (blocks 5120..6143).
// ---------------------------------------------------------------------------
__global__ __launch_bounds__(256) void prep(
    const float* __restrict__ X, const float* __restrict__ W1,
    const float* __restrict__ W2, bf16_t* __restrict__ Xb,
    bf16_t* __restrict__ Wt1, bf16_t* __restrict__ Wt2) {
  __shared__ float t[32][33];
  const int id = blockIdx.x, tid = threadIdx.x;
  if (id < 2048) {
    const float* src = X + (size_t)id * 4096;
    bf16_t* dst = Xb + (size_t)id * 4096;
#pragma unroll
    for (int i = 0; i < 4; ++i) {
      float4 v = *(const float4*)(src + i * 1024 + tid * 4);
      bf16x4 o;
      o[0] = (bf16_t)v.x; o[1] = (bf16_t)v.y; o[2] = (bf16_t)v.z; o[3] = (bf16_t)v.w;
      *(bf16x4*)(dst + i * 1024 + tid * 4) = o;
    }
    return;
  }
  const float* in; bf16_t* out; int R, C, bx, by;
  if (id < 5120) {  // W1 [1024][3072] -> Wt1 [3072][1024]
    int tI = id - 2048; R = 1024; C = 3072; in = W1; out = Wt1;
    bx = (tI % 96) * 32; by = (tI / 96) * 32;
  } else {          // W2 [1024][1024] -> Wt2 [1024][1024]
    int tI = id - 5120; R = 1024; C = 1024; in = W2; out = Wt2;
    bx = (tI % 32) * 32; by = (tI / 32) * 32;
  }
  int tx = tid & 31, ty = tid >> 5;
#pragma unroll
  for (int i = 0; i < 32; i += 8)
    t[ty + i][tx] = in[(size_t)(by + ty + i) * C + bx + tx];
  __syncthreads();
#pragma unroll
  for (int i = 0; i < 32; i += 8)
    out[(size_t)(bx + ty + i) * R + by + tx] = (bf16_t)t[tx][ty + i];
}

// ---------------------------------------------------------------------------
// GEMM main loop (m97 structure, BK=32) — used by gemm_qkv and gemm_proj.
// ---------------------------------------------------------------------------
DI void gemm_main(const bf16_t* __restrict__ A, const bf16_t* __restrict__ Bt,
                  int K, f32x4 acc[4][4], bf16_t* As, bf16_t* Bs,
                  int lane, int w) {
  const int wy = w >> 1, wx = w & 1;
  const int l15 = lane & 15, quad = lane >> 4;
  for (int kt = 0; kt < K; kt += 32) {
    __syncthreads();
#pragma unroll
    for (int i = 0; i < 2; ++i) {
      int g = w * 2 + i;
      int row = g * 16 + (lane >> 2);
      int ko = kt + (lane & 3) * 8;
      gl2lds16(A + (size_t)row * K + ko, As + g * 512 + lane * 8);
      gl2lds16(Bt + (size_t)row * K + ko, Bs + g * 512 + lane * 8);
    }
    __syncthreads();
    bf16x8 af[4], bfr[4];
#pragma unroll
    for (int mi = 0; mi < 4; ++mi)
      af[mi] = *(const bf16x8*)(As + (wy * 64 + mi * 16 + l15) * 32 + quad * 8);
#pragma unroll
    for (int ni = 0; ni < 4; ++ni)
      bfr[ni] = *(const bf16x8*)(Bs + (wx * 64 + ni * 16 + l15) * 32 + quad * 8);
#pragma unroll
    for (int mi = 0; mi < 4; ++mi)
#pragma unroll
      for (int ni = 0; ni < 4; ++ni)
        acc[mi][ni] = __builtin_amdgcn_mfma_f32_16x16x32_bf16(
            af[mi], bfr[ni], acc[mi][ni], 0, 0, 0);
  }
}

// ---------------------------------------------------------------------------
// k2: QKV GEMM (R7 epilogue/structure). Grid (64,24): x = M-tile (fast).
// ---------------------------------------------------------------------------
__global__ __launch_bounds__(256) void gemm_qkv(
    const bf16_t* __restrict__ X, const bf16_t* __restrict__ Wt,
    const float* __restrict__ bias, bf16_t* __restrict__ qw,
    bf16_t* __restrict__ kw, bf16_t* __restrict__ vtw) {
  __shared__ __align__(16) bf16_t As[128 * 32];
  __shared__ __align__(16) bf16_t Bs[128 * 32];
  const int tid = threadIdx.x, lane = tid & 63, w = tid >> 6;
  const int m0 = blockIdx.x * 128, n0 = blockIdx.y * 128;
  f32x4 acc[4][4];
#pragma unroll
  for (int mi = 0; mi < 4; ++mi)
#pragma unroll
    for (int ni = 0; ni < 4; ++ni) acc[mi][ni] = (f32x4){0.f, 0.f, 0.f, 0.f};
  gemm_main(X + (size_t)m0 * NXq, Wt + (size_t)n0 * NXq, NXq, acc, As, Bs, lane, w);

  const int wy = w >> 1, wx = w & 1, l15 = lane & 15, quad = lane >> 4;
  const float qscale = 0.125f * 1.44269504088896340736f;
#pragma unroll
  for (int mi = 0; mi < 4; ++mi) {
    int rowb = m0 + wy * 64 + mi * 16 + quad * 4;
    int bb = rowb >> 11, sl = rowb & 2047;
#pragma unroll
    for (int ni = 0; ni < 4; ++ni) {
      int col = n0 + wx * 64 + ni * 16 + l15;
      float bv = bias[col];
      f32x4 v = acc[mi][ni];
      int sec = col >> 10;
      int c = col & 1023;
      int h = c >> 6, d = c & 63;
      if (sec == 0) {
#pragma unroll
        for (int r = 0; r < 4; ++r)
          qw[(((size_t)bb * NHq + h) * Sq + sl + r) * HDq + d] =
              (bf16_t)((v[r] + bv) * qscale);
      } else if (sec == 1) {
#pragma unroll
        for (int r = 0; r < 4; ++r)
          kw[(((size_t)bb * NHq + h) * Sq + sl + r) * HDq + d] = (bf16_t)(v[r] + bv);
      } else {
        bf16x4 t;
#pragma unroll
        for (int r = 0; r < 4; ++r) t[r] = (bf16_t)(v[r] + bv);
        *(bf16x4*)(vtw + (((size_t)bb * NHq + h) * HDq + d) * Sq + sl) = t;
      }
    }
  }
}

// ---------------------------------------------------------------------------
// k3: flash attention, causal. R12 version: swapped-QK^T in-register softmax
// (T12), sigma K-row staging, double-buffered K/V, 4 blocks/CU.
// ---------------------------------------------------------------------------
__global__ __launch_bounds__(256, 4) void attn_fwd(
    const bf16_t* __restrict__ qw, const bf16_t* __restrict__ kw,
    const bf16_t* __restrict__ vtw, bf16_t* __restrict__ aw) {
  __shared__ __align__(16) bf16_t Ks[2][4096], Vs[2][4096];
  const int tid = threadIdx.x, lane = tid & 63, w = tid >> 6;
  const int l15 = lane & 15, quad = lane >> 4;
  const int q2b = quad >> 1;  // lane bit 5

  const int id = blockIdx.x;
  const int bh = ((id & 7) << 3) | ((id >> 3) & 7);
  const int k4 = (id >> 6) & 3, quarter = id >> 8;
  int qtile;
  if (quarter == 0)      qtile = 15 - k4;
  else if (quarter == 1) qtile = 8 + k4;
  else if (quarter == 2) qtile = 7 - k4;
  else                   qtile = k4;
  const int b = bh >> 4, h = bh & 15;

  const bf16_t* Qg = qw + ((size_t)bh * Sq + qtile * 128) * HDq;
  const bf16_t* Kg = kw + (size_t)bh * Sq * HDq;
  const bf16_t* Vg = vtw + (size_t)bh * HDq * Sq;

  bf16x8 qf[2][2];
#pragma unroll
  for (int mi = 0; mi < 2; ++mi)
#pragma unroll
    for (int ks = 0; ks < 2; ++ks)
      qf[mi][ks] = *(const bf16x8*)(
          Qg + (size_t)((w * 2 + mi) * 16 + l15) * HDq + ks * 32 + quad * 8);

  f32x4 o[2][4];
  float ls[2] = {0.f, 0.f};
#pragma unroll
  for (int mi = 0; mi < 2; ++mi)
#pragma unroll
    for (int dt = 0; dt < 4; ++dt) o[mi][dt] = (f32x4){0.f, 0.f, 0.f, 0.f};

  // per-wave staging: 2 K-units + 2 V-units.
  // K rows permuted by sigma = swap bits 2<->3 of row-in-16 (global source
  // only; LDS linear) so the PV A-frag is half lane-local.
  const int u0 = w * 2, u1 = w * 2 + 1;
  const int p0 = u0 >> 2, g0 = u0 & 3, p1 = u1 >> 2, g1 = u1 & 3;
  const int rin = lane >> 2;
  const int sig = (rin & 3) | ((rin & 4) << 1) | ((rin & 8) >> 1);
  const size_t kOff0 = (size_t)(g0 * 16 + sig) * HDq + p0 * 32 + (lane & 3) * 8;
  const size_t kOff1 = (size_t)(g1 * 16 + sig) * HDq + p1 * 32 + (lane & 3) * 8;
  const size_t vRow0 = (size_t)(g0 * 16 + rin) * Sq + p0 * 32 + (lane & 3) * 8;
  const size_t vRow1 = (size_t)(g1 * 16 + rin) * Sq + p1 * 32 + (lane & 3) * 8;

  const int jmax = 2 * qtile + 2;

  // prologue: stage tile 0 into buf 0
  gl2lds16(Kg + kOff0,  &Ks[0][u0 * 512 + lane * 8]);
  gl2lds16(Vg + vRow0,  &Vs[0][u0 * 512 + lane * 8]);
  gl2lds16(Kg + kOff1,  &Ks[0][u1 * 512 + lane * 8]);
  gl2lds16(Vg + vRow1,  &Vs[0][u1 * 512 + lane * 8]);

  for (int jt = 0; jt < jmax; ++jt) {
    const int cur = jt & 1;
    // own loads for buf[cur] issued a full iteration ago -> cheap wait
    asm volatile("s_waitcnt vmcnt(0)" ::: "memory");
    __builtin_amdgcn_s_barrier();
    if (jt + 1 < jmax) {
      const int nb = cur ^ 1;
      gl2lds16(Kg + (size_t)(jt + 1) * 64 * HDq + kOff0, &Ks[nb][u0 * 512 + lane * 8]);
      gl2lds16(Vg + vRow0 + (size_t)(jt + 1) * 64,       &Vs[nb][u0 * 512 + lane * 8]);
      gl2lds16(Kg + (size_t)(jt + 1) * 64 * HDq + kOff1, &Ks[nb][u1 * 512 + lane * 8]);
      gl2lds16(Vg + vRow1 + (size_t)(jt + 1) * 64,       &Vs[nb][u1 * 512 + lane * 8]);
    }
    const bf16_t* Kc = &Ks[cur][0];
    const bf16_t* Vc = &Vs[cur][0];

    // ---- QK^T, SWAPPED operands: sc[mi][nt] lane(l15,quad)[r] =
    //      S[q=(w*2+mi)*16+l15][key = jt*64 + nt*16 + sigma(quad*4+r)]
    f32x4 sc[2][4];
#pragma unroll
    for (int mi = 0; mi < 2; ++mi)
#pragma unroll
      for (int nt = 0; nt < 4; ++nt) sc[mi][nt] = (f32x4){0.f, 0.f, 0.f, 0.f};
    __builtin_amdgcn_s_setprio(1);
#pragma unroll
    for (int ks = 0; ks < 2; ++ks)
#pragma unroll
      for (int nt = 0; nt < 4; ++nt) {
        bf16x8 kf = *(const bf16x8*)(Kc + ks * 2048 + nt * 512 + (l15 * 4 + quad) * 8);
        sc[0][nt] = __builtin_amdgcn_mfma_f32_16x16x32_bf16(kf, qf[0][ks], sc[0][nt], 0, 0, 0);
        sc[1][nt] = __builtin_amdgcn_mfma_f32_16x16x32_bf16(kf, qf[1][ks], sc[1][nt], 0, 0, 0);
      }
    __builtin_amdgcn_s_setprio(0);

    // causal mask: key = jt*64 + nt*16 + 8*(quad&1) + 4*(quad>>1) + r
    if (jt >= 2 * qtile) {
      const int kb = jt * 64 + ((quad & 1) << 3) + (q2b << 2);
#pragma unroll
      for (int mi = 0; mi < 2; ++mi) {
        int qrow = qtile * 128 + (w * 2 + mi) * 16 + l15;
#pragma unroll
        for (int nt = 0; nt < 4; ++nt)
#pragma unroll
          for (int r = 0; r < 4; ++r)
            if (kb + nt * 16 + r > qrow) sc[mi][nt][r] = -1e30f;
      }
    }

    // ---- in-register P: exp2, pack to bf16, half-local + one xor32 swap.
    bf16x8 pa[2][2];
#pragma unroll
    for (int mi = 0; mi < 2; ++mi) {
      float pv[4][4];
#pragma unroll
      for (int nt = 0; nt < 4; ++nt)
#pragma unroll
        for (int r = 0; r < 4; ++r) {
          float p = fast_exp2(sc[mi][nt][r]);
          pv[nt][r] = p;
          ls[mi] += p;
        }
      u32 c0[4], c1[4];
#pragma unroll
      for (int nt = 0; nt < 4; ++nt) {
        c0[nt] = pk_bf16(pv[nt][0], pv[nt][1]);
        c1[nt] = pk_bf16(pv[nt][2], pv[nt][3]);
      }
#pragma unroll
      for (int kk = 0; kk < 2; ++kk) {
        // own: register nt = 2kk+q2, covers j in [4*q2, 4*q2+4)
        u32 oc0 = q2b ? c0[2 * kk + 1] : c0[2 * kk];
        u32 oc1 = q2b ? c1[2 * kk + 1] : c1[2 * kk];
        // send the register the xor32 partner needs (its nt = 2kk + own q2)
        u32 sd0 = q2b ? c0[2 * kk] : c0[2 * kk + 1];
        u32 sd1 = q2b ? c1[2 * kk] : c1[2 * kk + 1];
        u32 rc0 = (u32)__shfl_xor((int)sd0, 32);
        u32 rc1 = (u32)__shfl_xor((int)sd1, 32);
        u32x4 wv;
        wv[0] = q2b ? rc0 : oc0;
        wv[1] = q2b ? rc1 : oc1;
        wv[2] = q2b ? oc0 : rc0;
        wv[3] = q2b ? oc1 : rc1;
        pa[mi][kk] = __builtin_bit_cast(bf16x8, wv);
      }
    }

    // ---- PV
    __builtin_amdgcn_s_setprio(1);
#pragma unroll
    for (int kk = 0; kk < 2; ++kk) {
#pragma unroll
      for (int dt = 0; dt < 4; ++dt) {
        bf16x8 bv = *(const bf16x8*)(Vc + kk * 2048 + dt * 512 + (l15 * 4 + quad) * 8);
        o[0][dt] = __builtin_amdgcn_mfma_f32_16x16x32_bf16(pa[0][kk], bv, o[0][dt], 0, 0, 0);
        o[1][dt] = __builtin_amdgcn_mfma_f32_16x16x32_bf16(pa[1][kk], bv, o[1][dt], 0, 0, 0);
      }
    }
    __builtin_amdgcn_s_setprio(0);
  }

  // row sums: cross-quad reduce, then redistribute per output row.
  float linv[2][4];
#pragma unroll
  for (int mi = 0; mi < 2; ++mi) {
    float s = ls[mi];
    s += __shfl_xor(s, 16);
    s += __shfl_xor(s, 32);
#pragma unroll
    for (int r = 0; r < 4; ++r)
      linv[mi][r] = 1.f / __shfl(s, quad * 4 + r);
  }

#pragma unroll
  for (int mi = 0; mi < 2; ++mi) {
    int s0 = qtile * 128 + (w * 2 + mi) * 16 + quad * 4;
#pragma unroll
    for (int dt = 0; dt < 4; ++dt) {
      int col = h * 64 + dt * 16 + l15;
#pragma unroll
      for (int r = 0; r < 4; ++r)
        aw[((size_t)b * Sq + s0 + r) * NXq + col] = (bf16_t)(o[mi][dt][r] * linv[mi][r]);
    }
  }
}

// ---------------------------------------------------------------------------
// k4: output projection GEMM -> fp32 out + bias (unchanged).
// ---------------------------------------------------------------------------
__global__ __launch_bounds__(256) void gemm_proj(
    const bf16_t* __restrict__ Aa, const bf16_t* __restrict__ Wt,
    const float* __restrict__ bias, float* __restrict__ out) {
  __shared__ __align__(16) bf16_t As[128 * 32];
  __shared__ __align__(16) bf16_t Bs[128 * 32];
  const int tid = threadIdx.x, lane = tid & 63, w = tid >> 6;
  const int m0 = blockIdx.x * 128, n0 = blockIdx.y * 128;
  f32x4 acc[4][4];
#pragma unroll
  for (int mi = 0; mi < 4; ++mi)
#pragma unroll
    for (int ni = 0; ni < 4; ++ni) acc[mi][ni] = (f32x4){0.f, 0.f, 0.f, 0.f};
  gemm_main(Aa + (size_t)m0 * NXq, Wt + (size_t)n0 * NXq, NXq, acc, As, Bs, lane, w);

  const int wy = w >> 1, wx = w & 1, l15 = lane & 15, quad = lane >> 4;
#pragma unroll
  for (int mi = 0; mi < 4; ++mi) {
    int rowb = m0 + wy * 64 + mi * 16 + quad * 4;
#pragma unroll
    for (int ni = 0; ni < 4; ++ni) {
      int col = n0 + wx * 64 + ni * 16 + l15;
      float bv = bias[col];
#pragma unroll
      for (int r = 0; r < 4; ++r)
        out[(size_t)(rowb + r) * NXq + col] = acc[mi][ni][r] + bv;
    }
  }
}

// ---------------------------------------------------------------------------
// launch
// ---------------------------------------------------------------------------
extern "C" void kernel_launch(void* const* d_in, const int* in_sizes, int n_in,
                              void* d_out, int out_size, void* d_ws, size_t ws_size,
                              hipStream_t stream) {
  const float* hidden   = (const float*)d_in[0];
  const float* c_attn_w = (const float*)d_in[1];
  const float* c_attn_b = (const float*)d_in[2];
  const float* c_proj_w = (const float*)d_in[3];
  const float* c_proj_b = (const float*)d_in[4];
  float* out = (float*)d_out;

  char* ws = (char*)d_ws;
  const size_t szX   = (size_t)8192 * 1024 * 2;
  const size_t szW1  = (size_t)3072 * 1024 * 2;
  const size_t szW2  = (size_t)1024 * 1024 * 2;
  const size_t szQKV = (size_t)Bq * NHq * Sq * HDq * 2;
  bf16_t* Xb  = (bf16_t*)(ws);
  bf16_t* Wt1 = (bf16_t*)(ws + szX);
  bf16_t* Wt2 = (bf16_t*)(ws + szX + szW1);
  bf16_t* qwp = (bf16_t*)(ws + szX + szW1 + szW2);
  bf16_t* kwp = (bf16_t*)(ws + szX + szW1 + szW2 + szQKV);
  bf16_t* vtp = (bf16_t*)(ws + szX + szW1 + szW2 + 2 * szQKV);
  bf16_t* awp = (bf16_t*)(ws + szX + szW1 + szW2 + 3 * szQKV);
  if (ws_size < szX + szW1 + szW2 + 4 * szQKV) return;

  prep<<<dim3(6144), dim3(256), 0, stream>>>(hidden, c_attn_w, c_proj_w,
                                             Xb, Wt1, Wt2);
  gemm_qkv<<<dim3(64, 24), dim3(256), 0, stream>>>(
      Xb, Wt1, c_attn_b, qwp, kwp, vtp);
  attn_fwd<<<dim3(1024), dim3(256), 0, stream>>>(qwp, kwp, vtp, awp);
  gemm_proj<<<dim3(64, 8), dim3(256), 0, stream>>>(
      awp, Wt2, c_proj_b, out);
}